// Round 3
// baseline (306.801 us; speedup 1.0000x reference)
//
#include <hip/hip_runtime.h>
#include <cstdint>

typedef unsigned short u16;
typedef __bf16 bf16x8 __attribute__((ext_vector_type(8)));
typedef float f32x4 __attribute__((ext_vector_type(4)));

__device__ __forceinline__ u16 f2bf(float f) {
  __bf16 h = (__bf16)f;               // HW v_cvt (RNE) on gfx950
  return __builtin_bit_cast(u16, h);
}
__device__ __forceinline__ float bf2f(u16 u) {
  union { uint32_t u; float f; } v; v.u = ((uint32_t)u) << 16;
  return v.f;
}

// async global->LDS, 16B per lane. LDS dest is wave-uniform base + lane*16.
__device__ __forceinline__ void gload16(const void* g, const void* l) {
  __builtin_amdgcn_global_load_lds(
      (const __attribute__((address_space(1))) uint32_t*)(uintptr_t)g,
      (__attribute__((address_space(3))) uint32_t*)(uintptr_t)l, 16, 0, 0);
}

__device__ __forceinline__ f32x4 mfma16(bf16x8 a, bf16x8 b, f32x4 c) {
  return __builtin_amdgcn_mfma_f32_16x16x32_bf16(a, b, c, 0, 0, 0);
}

// swizzled LDS offset for logical (row, col) in a [*][64] bf16 tile (attn):
__device__ __forceinline__ int swz(int row, int col) {
  return row * 64 + ((((col >> 3) ^ (row & 7)) << 3) | (col & 7));
}

// ---------------- convert fp32 -> bf16 (vectorized) ----------------
__global__ __launch_bounds__(256)
void k_cvt(const float* __restrict__ src, u16* __restrict__ dst, int n4) {
  int i = blockIdx.x * 256 + threadIdx.x;
  if (i >= n4) return;
  float4 v = ((const float4*)src)[i];
  union { u16 s[4]; uint2 u; } o;
  o.s[0] = f2bf(v.x); o.s[1] = f2bf(v.y); o.s[2] = f2bf(v.z); o.s[3] = f2bf(v.w);
  ((uint2*)dst)[i] = o.u;
}

// ------------- transpose fp32 [R][C] -> bf16 [C][R] (64x64 tiles) -------------
__global__ __launch_bounds__(256)
void k_transpose(const float* __restrict__ src, u16* __restrict__ dst, int R, int Cc) {
  __shared__ u16 t[64 * 66];
  int r0 = blockIdx.y * 64, c0 = blockIdx.x * 64;
  #pragma unroll
  for (int i = 0; i < 16; i++) {
    int e = i * 256 + threadIdx.x;
    int rl = e >> 6, cl = e & 63;
    t[cl * 66 + rl] = f2bf(src[(size_t)(r0 + rl) * Cc + c0 + cl]);
  }
  __syncthreads();
  #pragma unroll
  for (int i = 0; i < 16; i++) {
    int e = i * 256 + threadIdx.x;
    int ro = e >> 6, co = e & 63;
    dst[(size_t)(c0 + ro) * R + r0 + co] = t[ro * 66 + co];
  }
}

// ----- temb projection, stage 1 -----
__global__ __launch_bounds__(256)
void k_temb_part(const float* __restrict__ temb, const float* __restrict__ Wt,
                 float* __restrict__ part) {
  const int j = blockIdx.x * 256 + threadIdx.x;   // 0..3071
  const int k0 = blockIdx.y * 32;
  float acc[8];
  #pragma unroll
  for (int b = 0; b < 8; b++) acc[b] = 0.f;
  #pragma unroll 4
  for (int k = k0; k < k0 + 32; k++) {
    float wv = Wt[(size_t)k * 3072 + j];
    #pragma unroll
    for (int b = 0; b < 8; b++) acc[b] += temb[b * 1024 + k] * wv;
  }
  float* p = part + (size_t)blockIdx.y * 24576 + j;
  #pragma unroll
  for (int b = 0; b < 8; b++) p[b * 3072] = acc[b];
}

// ----- temb projection, stage 2 -----
__global__ __launch_bounds__(256)
void k_temb_red(const float* __restrict__ part, const float* __restrict__ bt,
                const float* __restrict__ bqkv, float* __restrict__ tcomb) {
  const int j = blockIdx.x * 256 + threadIdx.x;   // 0..3071
  const int b = blockIdx.y;
  const float* p = part + b * 3072 + j;
  float a = bt[j] + bqkv[j];
  #pragma unroll
  for (int kt = 0; kt < 32; kt++) a += p[(size_t)kt * 24576];
  tcomb[b * 3072 + j] = a;
}

// ------------- bf16 MFMA GEMM: C[M][Ntot] = A[M][K] @ Bt[N][K]^T -------------
// Session-best core: block 256M x 128N, 4 waves, wave tile 64M x 128N,
// BK=32, double-buffered LDS (48 KiB -> multi-block/CU), 1 barrier/iter.
// MODE 0: FUSED epilogue = bias + per-head RMSNorm + axial RoPE + Q-prescale
//         (Q/K blocks) or bias + LDS-transpose -> VT (V blocks). Replaces k_rrv.
//         Head-alignment: 128 N-cols = 2 heads; RoPE partner d^16 = acc[i][j^1][r]
//         (in-thread); 64-col sumsq = 4 in-thread sq + 16-lane shfl reduce.
// MODE 1: plain fp32 out + bias (proj GEMM).
template <int MODE>
__global__ __launch_bounds__(256, 2)
void k_gemm(const u16* __restrict__ A, const u16* __restrict__ Bt,
            float* __restrict__ outf, const float* __restrict__ bias,
            int K, int Ntot,
            const float* __restrict__ cos_y, const float* __restrict__ sin_y,
            const float* __restrict__ cos_x, const float* __restrict__ sin_x,
            const float* __restrict__ qn_w, const float* __restrict__ kn_w,
            u16* __restrict__ Qo, u16* __restrict__ Ko, u16* __restrict__ VTo) {
  __shared__ u16 SM[24576];                     // As[2][8192] | Bs[2][4096]
  u16* As = SM;
  u16* Bs = SM + 16384;
  const int m0 = blockIdx.y * 256;
  const int n0 = blockIdx.x * 128;
  const int lane = threadIdx.x & 63;
  const int w = threadIdx.x >> 6;
  const int l15 = lane & 15;
  const int fo = (((lane >> 4) ^ ((lane >> 1) & 3)) << 3);
  const int srow = lane >> 2;
  const int schunk = (((lane & 3) ^ ((lane >> 3) & 3)) << 3);

  f32x4 acc[4][8];
  #pragma unroll
  for (int i = 0; i < 4; i++)
    #pragma unroll
    for (int j = 0; j < 8; j++) acc[i][j] = (f32x4){0.f, 0.f, 0.f, 0.f};

  const u16* Ag = A + (size_t)(m0 + srow) * K + schunk;
  const u16* Bg = Bt + (size_t)(n0 + srow) * K + schunk;

  const int iters = K >> 5;
  #pragma unroll
  for (int tt = 0; tt < 4; tt++) {
    int t = w * 4 + tt;
    gload16(Ag + (size_t)(16 * t) * K, &As[t * 512]);
  }
  #pragma unroll
  for (int tt = 0; tt < 2; tt++) {
    int t = w * 2 + tt;
    gload16(Bg + (size_t)(16 * t) * K, &Bs[t * 512]);
  }

  for (int it = 0; it < iters; it++) {
    __syncthreads();
    const int cur = it & 1;
    if (it + 1 < iters) {
      const int nxt = cur ^ 1;
      const int k1 = (it + 1) << 5;
      #pragma unroll
      for (int tt = 0; tt < 4; tt++) {
        int t = w * 4 + tt;
        gload16(Ag + (size_t)(16 * t) * K + k1, &As[nxt * 8192 + t * 512]);
      }
      #pragma unroll
      for (int tt = 0; tt < 2; tt++) {
        int t = w * 2 + tt;
        gload16(Bg + (size_t)(16 * t) * K + k1, &Bs[nxt * 4096 + t * 512]);
      }
    }
    bf16x8 af[4], bfr[8];
    #pragma unroll
    for (int i = 0; i < 4; i++)
      af[i] = *(const bf16x8*)&As[cur * 8192 + (w * 64 + 16 * i + l15) * 32 + fo];
    #pragma unroll
    for (int j = 0; j < 8; j++)
      bfr[j] = *(const bf16x8*)&Bs[cur * 4096 + (16 * j + l15) * 32 + fo];
    #pragma unroll
    for (int i = 0; i < 4; i++)
      #pragma unroll
      for (int j = 0; j < 8; j++)
        acc[i][j] = mfma16(af[i], bfr[j], acc[i][j]);
  }

  const int rl = (lane >> 4) * 4;

  if (MODE == 1) {
    #pragma unroll
    for (int i = 0; i < 4; i++)
      #pragma unroll
      for (int j = 0; j < 8; j++)
        #pragma unroll
        for (int r = 0; r < 4; r++) {
          int grow = m0 + w * 64 + 16 * i + rl + r;
          int gcol = n0 + 16 * j + l15;
          outf[(size_t)grow * Ntot + gcol] = acc[i][j][r] + bias[gcol];
        }
    return;
  }

  // ---------------- MODE 0: fused QKV epilogue ----------------
  const int bidx = m0 >> 10;                    // batch (256 | 1024)
  float tc[8];
  #pragma unroll
  for (int j = 0; j < 8; j++) tc[j] = bias[bidx * 3072 + n0 + 16 * j + l15];

  if (n0 < 2048) {                              // ---- Q or K blocks ----
    const bool isQ = (n0 < 1024);
    u16* dst = isQ ? Qo : Ko;
    const float* nw = isQ ? qn_w : kn_w;
    const float osc = isQ ? 0.18033688011112042f : 1.0f;   // log2(e)/8
    const int hbase = (n0 & 1023) >> 6;         // head of j<4 (j>=4 -> +1)
    float wv[8];
    #pragma unroll
    for (int j = 0; j < 8; j++) wv[j] = nw[(16 * j + l15) & 63];

    #pragma unroll
    for (int i = 0; i < 4; i++) {
      #pragma unroll
      for (int r = 0; r < 4; r++) {
        int grow = m0 + w * 64 + 16 * i + rl + r;
        int n = grow & 1023;
        float v[8];
        #pragma unroll
        for (int j = 0; j < 8; j++) v[j] = acc[i][j][r] + tc[j];
        float sA = v[0]*v[0] + v[1]*v[1] + v[2]*v[2] + v[3]*v[3];
        float sB = v[4]*v[4] + v[5]*v[5] + v[6]*v[6] + v[7]*v[7];
        #pragma unroll
        for (int m = 1; m < 16; m <<= 1) {
          sA += __shfl_xor(sA, m);
          sB += __shfl_xor(sB, m);
        }
        float rA = rsqrtf(sA * (1.0f / 64.0f) + 1e-6f);
        float rB = rsqrtf(sB * (1.0f / 64.0f) + 1e-6f);
        float u[8];
        #pragma unroll
        for (int j = 0; j < 8; j++) u[j] = v[j] * (j < 4 ? rA : rB) * wv[j];
        const float* cy = cos_y + (size_t)n * 32;
        const float* sy = sin_y + (size_t)n * 32;
        const float* cx = cos_x + (size_t)n * 32;
        const float* sx = sin_x + (size_t)n * 32;
        #pragma unroll
        for (int j = 0; j < 8; j++) {
          int dh = ((j & 1) << 4) + l15;        // d & 31
          float c = (j & 2) ? cx[dh] : cy[dh];
          float s = (j & 2) ? sx[dh] : sy[dh];
          float sgn = (j & 1) ? 1.0f : -1.0f;   // rotate_half: d<16 -> -t[d+16]
          float o = (u[j] * c + sgn * u[j ^ 1] * s) * osc;
          int h = hbase + (j >> 2);
          int d = (16 * j + l15) & 63;
          dst[((size_t)(bidx * 16 + h) * 1024 + n) * 64 + d] = f2bf(o);
        }
      }
    }
  } else {                                      // ---- V blocks: LDS transpose -> VT ----
    __syncthreads();                            // K-loop LDS reads done everywhere
    u16* T = SM;                                // [128 d][136] u16 = 34816 B
    const int vbase = bidx * 1024 + (n0 & 1023);   // VT row base (= bh*64 + d)
    const int nb0 = m0 & 1023;
    #pragma unroll
    for (int p = 0; p < 2; p++) {
      if ((w >> 1) == p) {
        #pragma unroll
        for (int i = 0; i < 4; i++)
          #pragma unroll
          for (int j = 0; j < 8; j++)
            #pragma unroll
            for (int r = 0; r < 4; r++) {
              int nl = (w & 1) * 64 + 16 * i + rl + r;   // 0..127 within pass
              T[(16 * j + l15) * 136 + nl] = f2bf(acc[i][j][r] + tc[j]);
            }
      }
      __syncthreads();
      #pragma unroll
      for (int itr = 0; itr < 8; itr++) {
        int e = itr * 256 + threadIdx.x;
        int row = e >> 4, ch = e & 15;
        uint4 val = *(const uint4*)&T[row * 136 + ch * 8];
        *(uint4*)(VTo + ((size_t)(vbase + row)) * 1024 + nb0 + p * 128 + ch * 8) = val;
      }
      __syncthreads();
    }
  }
}

// ---------------- flash attention, 128 q-rows/block, dbuf K/V, 1 barrier/iter ----------------
__global__ __launch_bounds__(256, 2)
void k_attn(const u16* __restrict__ Q, const u16* __restrict__ Kb,
            const u16* __restrict__ VT, u16* __restrict__ Ob) {
  __shared__ u16 Ks[2][4096], VTs[2][4096], Ps[4][2048];
  const int lane = threadIdx.x & 63;
  const int w = threadIdx.x >> 6;
  const int bh = blockIdx.x;
  const int qt = blockIdx.y;
  const int b = bh >> 4, h = bh & 15;
  const size_t base = (size_t)bh * 65536;
  const int q0 = qt * 128;
  const int scol = ((lane & 7) ^ (lane >> 3)) * 8;
  const int lr = lane >> 3;

  bf16x8 aq[2][2];
  #pragma unroll
  for (int i = 0; i < 2; i++)
    #pragma unroll
    for (int s = 0; s < 2; s++)
      aq[i][s] = *(const bf16x8*)(Q + base +
          (size_t)(q0 + w * 32 + i * 16 + (lane & 15)) * 64 + s * 32 + (lane >> 4) * 8);

  f32x4 acc_o[2][4];
  float lpar[2][4];
  #pragma unroll
  for (int i = 0; i < 2; i++)
    #pragma unroll
    for (int r = 0; r < 4; r++) {
      acc_o[i][r] = (f32x4){0.f, 0.f, 0.f, 0.f};
      lpar[i][r] = 0.f;
    }

  #pragma unroll
  for (int tt = 0; tt < 2; tt++) {
    int t = w * 2 + tt;
    gload16(Kb + base + (size_t)(8 * t + lr) * 64 + scol, &Ks[0][t * 512]);
    gload16(VT + base + (size_t)(8 * t + lr) * 1024 + scol, &VTs[0][t * 512]);
  }

  for (int it = 0; it < 16; it++) {
    __syncthreads();
    const int cur = it & 1;
    if (it < 15) {
      const int nxt = cur ^ 1;
      const int j1 = (it + 1) * 64;
      #pragma unroll
      for (int tt = 0; tt < 2; tt++) {
        int t = w * 2 + tt;
        gload16(Kb + base + (size_t)(j1 + 8 * t + lr) * 64 + scol, &Ks[nxt][t * 512]);
        gload16(VT + base + (size_t)(8 * t + lr) * 1024 + j1 + scol, &VTs[nxt][t * 512]);
      }
    }
    const u16* K_ = Ks[cur];
    const u16* V_ = VTs[cur];

    f32x4 accs[2][4];
    #pragma unroll
    for (int i = 0; i < 2; i++)
      #pragma unroll
      for (int nt = 0; nt < 4; nt++) accs[i][nt] = (f32x4){0.f, 0.f, 0.f, 0.f};
    #pragma unroll
    for (int s = 0; s < 2; s++) {
      bf16x8 bk[4];
      #pragma unroll
      for (int nt = 0; nt < 4; nt++)
        bk[nt] = *(const bf16x8*)&K_[swz(nt * 16 + (lane & 15), s * 32 + (lane >> 4) * 8)];
      #pragma unroll
      for (int i = 0; i < 2; i++)
        #pragma unroll
        for (int nt = 0; nt < 4; nt++)
          accs[i][nt] = mfma16(aq[i][s], bk[nt], accs[i][nt]);
    }

    #pragma unroll
    for (int i = 0; i < 2; i++) {
      #pragma unroll
      for (int nt = 0; nt < 4; nt++) {
        #pragma unroll
        for (int r = 0; r < 4; r++) {
          float p = __builtin_amdgcn_exp2f(accs[i][nt][r]);
          lpar[i][r] += p;
          Ps[w][swz(i * 16 + (lane >> 4) * 4 + r, nt * 16 + (lane & 15))] = f2bf(p);
        }
      }
    }
    asm volatile("s_waitcnt lgkmcnt(0)" ::: "memory");

    #pragma unroll
    for (int s = 0; s < 2; s++) {
      bf16x8 bv[4];
      #pragma unroll
      for (int dt = 0; dt < 4; dt++)
        bv[dt] = *(const bf16x8*)&V_[swz(dt * 16 + (lane & 15), s * 32 + (lane >> 4) * 8)];
      #pragma unroll
      for (int i = 0; i < 2; i++) {
        bf16x8 ap = *(const bf16x8*)&Ps[w][swz(i * 16 + (lane & 15), s * 32 + (lane >> 4) * 8)];
        #pragma unroll
        for (int dt = 0; dt < 4; dt++)
          acc_o[i][dt] = mfma16(ap, bv[dt], acc_o[i][dt]);
      }
    }
  }

  #pragma unroll
  for (int i = 0; i < 2; i++) {
    float inv[4];
    #pragma unroll
    for (int r = 0; r < 4; r++) {
      float l = lpar[i][r];
      #pragma unroll
      for (int m = 1; m < 16; m <<= 1) l += __shfl_xor(l, m);
      inv[r] = 1.0f / l;
    }
    #pragma unroll
    for (int dt = 0; dt < 4; dt++)
      #pragma unroll
      for (int r = 0; r < 4; r++) {
        int row = q0 + w * 32 + i * 16 + (lane >> 4) * 4 + r;
        int col = h * 64 + dt * 16 + (lane & 15);
        Ob[((size_t)b * 1024 + row) * 1024 + col] = f2bf(acc_o[i][dt][r] * inv[r]);
      }
  }
}

// ---------------- launch ----------------
extern "C" void kernel_launch(void* const* d_in, const int* in_sizes, int n_in,
                              void* d_out, int out_size, void* d_ws, size_t ws_size,
                              hipStream_t stream) {
  const float* x     = (const float*)d_in[0];
  const float* temb  = (const float*)d_in[1];
  const float* cos_y = (const float*)d_in[2];
  const float* sin_y = (const float*)d_in[3];
  const float* cos_x = (const float*)d_in[4];
  const float* sin_x = (const float*)d_in[5];
  const float* Wqkv  = (const float*)d_in[6];
  const float* bqkv  = (const float*)d_in[7];
  const float* Wt    = (const float*)d_in[8];
  const float* bt    = (const float*)d_in[9];
  const float* Wp    = (const float*)d_in[10];
  const float* bp    = (const float*)d_in[11];
  const float* qn_w  = (const float*)d_in[12];
  const float* kn_w  = (const float*)d_in[13];
  float* out = (float*)d_out;

  char* ws = (char*)d_ws;
  u16*   x_bf  = (u16*)(ws);                  // 16 MB; reused as att after QKV GEMM
  u16*   WqkvT = (u16*)(ws + 16777216);       // 6 MB
  u16*   WpT   = (u16*)(ws + 23068672);       // 2 MB
  float* tcomb = (float*)(ws + 25165824);     // 96 KB
  u16*   Qb    = (u16*)(ws + 75595776);       // 16 MB
  u16*   Kb    = (u16*)(ws + 92372992);       // 16 MB
  u16*   VTb   = (u16*)(ws + 109150208);      // 16 MB
  float* tpart = (float*)(ws + 125927424);    // 3 MB
  u16*   att   = x_bf;

  k_cvt<<<8192, 256, 0, stream>>>(x, x_bf, 8192 * 1024 / 4);
  k_transpose<<<dim3(48, 16), 256, 0, stream>>>(Wqkv, WqkvT, 1024, 3072);
  k_transpose<<<dim3(16, 16), 256, 0, stream>>>(Wp, WpT, 1024, 1024);
  k_temb_part<<<dim3(12, 32), 256, 0, stream>>>(temb, Wt, tpart);
  k_temb_red<<<dim3(12, 8), 256, 0, stream>>>(tpart, bt, bqkv, tcomb);
  k_gemm<0><<<dim3(24, 32), 256, 0, stream>>>(
      x_bf, WqkvT, nullptr, tcomb, 1024, 3072,
      cos_y, sin_y, cos_x, sin_x, qn_w, kn_w, Qb, Kb, VTb);
  k_attn<<<dim3(128, 8), 256, 0, stream>>>(Qb, Kb, VTb, att);
  k_gemm<1><<<dim3(8, 32), 256, 0, stream>>>(
      att, WpT, out, bp, 1024, 1024,
      nullptr, nullptr, nullptr, nullptr, nullptr, nullptr,
      nullptr, nullptr, nullptr);
}

// Round 4
// 273.157 us; speedup vs baseline: 1.1232x; 1.1232x over previous
//
#include <hip/hip_runtime.h>
#include <cstdint>

typedef unsigned short u16;
typedef __bf16 bf16x8 __attribute__((ext_vector_type(8)));
typedef float f32x4 __attribute__((ext_vector_type(4)));

__device__ __forceinline__ u16 f2bf(float f) {
  __bf16 h = (__bf16)f;               // HW v_cvt (RNE) on gfx950
  return __builtin_bit_cast(u16, h);
}
__device__ __forceinline__ float bf2f(u16 u) {
  union { uint32_t u; float f; } v; v.u = ((uint32_t)u) << 16;
  return v.f;
}

// async global->LDS, 16B per lane. LDS dest is wave-uniform base + lane*16.
__device__ __forceinline__ void gload16(const void* g, const void* l) {
  __builtin_amdgcn_global_load_lds(
      (const __attribute__((address_space(1))) uint32_t*)(uintptr_t)g,
      (__attribute__((address_space(3))) uint32_t*)(uintptr_t)l, 16, 0, 0);
}

__device__ __forceinline__ f32x4 mfma16(bf16x8 a, bf16x8 b, f32x4 c) {
  return __builtin_amdgcn_mfma_f32_16x16x32_bf16(a, b, c, 0, 0, 0);
}

// swizzled LDS offset for logical (row, col) in a [*][64] bf16 tile:
// 16B chunks XORed by row&7 -> conflict-free b128 reads.
__device__ __forceinline__ int swz(int row, int col) {
  return row * 64 + ((((col >> 3) ^ (row & 7)) << 3) | (col & 7));
}

// ---------------- merged prep: cvt + 2 transposes + temb_part ----------------
__device__ __forceinline__ void transpose64(const float* __restrict__ src,
                                            u16* __restrict__ dst, int R, int Cc,
                                            int r0, int c0, u16* t) {
  #pragma unroll
  for (int i = 0; i < 16; i++) {
    int e = i * 256 + threadIdx.x;
    int rl = e >> 6, cl = e & 63;
    t[cl * 66 + rl] = f2bf(src[(size_t)(r0 + rl) * Cc + c0 + cl]);
  }
  __syncthreads();
  #pragma unroll
  for (int i = 0; i < 16; i++) {
    int e = i * 256 + threadIdx.x;
    int ro = e >> 6, co = e & 63;
    dst[(size_t)(c0 + ro) * R + r0 + co] = t[ro * 66 + co];
  }
}

// sections: [0,8192) cvt x->bf16 | [8192,8960) T(Wqkv) | [8960,9216) T(Wp)
//           [9216,9600) temb_part
__global__ __launch_bounds__(256)
void k_prep(const float* __restrict__ x, u16* __restrict__ x_bf,
            const float* __restrict__ Wqkv, u16* __restrict__ WqkvT,
            const float* __restrict__ Wp, u16* __restrict__ WpT,
            const float* __restrict__ temb, const float* __restrict__ Wt,
            float* __restrict__ tpart) {
  __shared__ u16 t[64 * 66];
  int bid = blockIdx.x;
  if (bid < 8192) {                              // ---- cvt (2M float4) ----
    int i = bid * 256 + threadIdx.x;
    float4 v = ((const float4*)x)[i];
    union { u16 s[4]; uint2 u; } o;
    o.s[0] = f2bf(v.x); o.s[1] = f2bf(v.y); o.s[2] = f2bf(v.z); o.s[3] = f2bf(v.w);
    ((uint2*)x_bf)[i] = o.u;
    return;
  }
  bid -= 8192;
  if (bid < 768) {                               // ---- transpose Wqkv [1024][3072] ----
    transpose64(Wqkv, WqkvT, 1024, 3072, (bid / 48) * 64, (bid % 48) * 64, t);
    return;
  }
  bid -= 768;
  if (bid < 256) {                               // ---- transpose Wp [1024][1024] ----
    transpose64(Wp, WpT, 1024, 1024, (bid / 16) * 64, (bid % 16) * 64, t);
    return;
  }
  bid -= 256;                                    // ---- temb_part (384 blocks) ----
  {
    const int j = (bid % 12) * 256 + threadIdx.x;   // 0..3071
    const int k0 = (bid / 12) * 32;
    float acc[8];
    #pragma unroll
    for (int b = 0; b < 8; b++) acc[b] = 0.f;
    #pragma unroll 4
    for (int k = k0; k < k0 + 32; k++) {
      float wv = Wt[(size_t)k * 3072 + j];
      #pragma unroll
      for (int b = 0; b < 8; b++) acc[b] += temb[b * 1024 + k] * wv;
    }
    float* p = tpart + (size_t)(bid / 12) * 24576 + j;
    #pragma unroll
    for (int b = 0; b < 8; b++) p[b * 3072] = acc[b];
  }
}

// ------------- bf16 MFMA GEMM: C[M][Ntot] = A[M][K] @ Bt[N][K]^T -------------
// 128M x 256N tile, BK=64, 8 waves (2M x 4N, wave tile 64x64).
// TRIPLE-buffered LDS, 2 phases/K-tile, counted vmcnt(6), setprio (R2 core).
// MODE 0: temb_red folded into prologue (tcs[256] in LDS, serialized before
//         staging so per-wave vmcnt counts stay exact); writes qkv bf16.
// MODE 1: plain fp32 out + bias.
template <int MODE>
__global__ __launch_bounds__(512, 2)
void k_gemm(const u16* __restrict__ A, const u16* __restrict__ Bt,
            u16* __restrict__ outb, float* __restrict__ outf,
            const float* __restrict__ bias,
            const float* __restrict__ bt, const float* __restrict__ bqkv,
            const float* __restrict__ tpart, int K, int Ntot) {
  __shared__ __align__(16) u16 As[3][128 * 64];   // 3 x 16 KiB
  __shared__ __align__(16) u16 Bs[3][256 * 64];   // 3 x 32 KiB
  __shared__ float tcs[256];                      // 1 KiB (MODE 0 bias slice)

  const int nb = (int)gridDim.x;
  const int bid = (int)blockIdx.x;
  const int sb = (bid & 7) * (nb >> 3) + (bid >> 3);
  const int NBN = Ntot >> 8;
  const int m0 = (sb / NBN) * 128;
  const int n0 = (sb % NBN) * 256;

  const int lane = threadIdx.x & 63;
  const int w = threadIdx.x >> 6;                 // 0..7
  const int wm = w >> 2;                          // 0..1  (64-row slab)
  const int wn = w & 3;                           // 0..3  (64-col slab)
  const int l15 = lane & 15;
  const int g8 = (lane >> 4) * 8;
  const int lr = lane >> 3;
  const int schunk = ((lane & 7) ^ lr) * 8;       // pre-swizzled global source chunk

  const u16* Ag = A + (size_t)(m0 + w * 16 + lr) * K + schunk;
  const u16* Bg = Bt + (size_t)(n0 + lr) * K + schunk;

  // ---- MODE 0: fold temb_red -> tcs (done BEFORE staging; its loads drain
  //      before any gload_lds issues, keeping counted vmcnt exact) ----
  if (MODE == 0) {
    if (threadIdx.x < 256) {
      const int bidx = m0 >> 10;
      const int j = n0 + (int)threadIdx.x;
      float a = bt[j] + bqkv[j];
      #pragma unroll
      for (int kt = 0; kt < 32; kt++) a += tpart[(size_t)kt * 24576 + bidx * 3072 + j];
      tcs[threadIdx.x] = a;
    }
    asm volatile("" ::: "memory");
  }

  f32x4 acc[4][4];
  #pragma unroll
  for (int i = 0; i < 4; i++)
    #pragma unroll
    for (int j = 0; j < 4; j++) acc[i][j] = (f32x4){0.f, 0.f, 0.f, 0.f};

  auto stageA_Blo = [&](int kt_, int buf_) {
    const int ko = kt_ << 6;
    #pragma unroll
    for (int t = 0; t < 2; t++) {
      int r0 = w * 16 + t * 8;
      gload16(Ag + (size_t)(t * 8) * K + ko, &As[buf_][r0 * 64]);
    }
    #pragma unroll
    for (int t = 0; t < 2; t++) {
      int f0 = w * 16 + t * 8;
      int r0 = (f0 >> 5) * 64 + (f0 & 31);
      gload16(Bg + (size_t)r0 * K + ko, &Bs[buf_][r0 * 64]);
    }
  };
  auto stageBhi = [&](int kt_, int buf_) {
    const int ko = kt_ << 6;
    #pragma unroll
    for (int t = 0; t < 2; t++) {
      int f0 = w * 16 + t * 8;
      int r0 = (f0 >> 5) * 64 + 32 + (f0 & 31);
      gload16(Bg + (size_t)r0 * K + ko, &Bs[buf_][r0 * 64]);
    }
  };

  const int NT = K >> 6;                          // 16
  stageA_Blo(0, 0); stageBhi(0, 0);
  stageA_Blo(1, 1); stageBhi(1, 1);
  asm volatile("s_waitcnt vmcnt(8)" ::: "memory");
  __builtin_amdgcn_s_barrier();
  asm volatile("" ::: "memory");

  int cur = 0;
  for (int kt = 0; kt < NT; kt++) {
    const int nxtbuf = cur + 2 >= 3 ? cur - 1 : cur + 2;

    // ---------------- phase 0: quadrant nf={0,1} ----------------
    bf16x8 af[2][4], bfr[2][4];
    #pragma unroll
    for (int s = 0; s < 2; s++)
      #pragma unroll
      for (int mf = 0; mf < 4; mf++)
        af[s][mf] = *(const bf16x8*)&As[cur][swz(wm * 64 + mf * 16 + l15, s * 32 + g8)];
    #pragma unroll
    for (int s = 0; s < 2; s++)
      #pragma unroll
      for (int nf = 0; nf < 2; nf++)
        bfr[s][nf] = *(const bf16x8*)&Bs[cur][swz(wn * 64 + nf * 16 + l15, s * 32 + g8)];
    if (kt + 2 < NT) stageA_Blo(kt + 2, nxtbuf);
    if (kt <= NT - 2) asm volatile("s_waitcnt vmcnt(6)" ::: "memory");
    else              asm volatile("s_waitcnt vmcnt(0)" ::: "memory");
    __builtin_amdgcn_s_barrier();
    asm volatile("" ::: "memory");
    __builtin_amdgcn_s_setprio(1);
    #pragma unroll
    for (int s = 0; s < 2; s++)
      #pragma unroll
      for (int mf = 0; mf < 4; mf++)
        #pragma unroll
        for (int nf = 0; nf < 2; nf++)
          acc[mf][nf] = mfma16(af[s][mf], bfr[s][nf], acc[mf][nf]);
    __builtin_amdgcn_s_setprio(0);

    // ---------------- phase 1: quadrant nf={2,3} ----------------
    #pragma unroll
    for (int s = 0; s < 2; s++)
      #pragma unroll
      for (int nf = 2; nf < 4; nf++)
        bfr[s][nf] = *(const bf16x8*)&Bs[cur][swz(wn * 64 + nf * 16 + l15, s * 32 + g8)];
    if (kt + 2 < NT) stageBhi(kt + 2, nxtbuf);
    if (kt < NT - 2)       asm volatile("s_waitcnt vmcnt(6)" ::: "memory");
    else if (kt == NT - 2) asm volatile("s_waitcnt vmcnt(2)" ::: "memory");
    else                   asm volatile("s_waitcnt vmcnt(0)" ::: "memory");
    __builtin_amdgcn_s_barrier();
    asm volatile("" ::: "memory");
    __builtin_amdgcn_s_setprio(1);
    #pragma unroll
    for (int s = 0; s < 2; s++)
      #pragma unroll
      for (int mf = 0; mf < 4; mf++)
        #pragma unroll
        for (int nf = 2; nf < 4; nf++)
          acc[mf][nf] = mfma16(af[s][mf], bfr[s][nf], acc[mf][nf]);
    __builtin_amdgcn_s_setprio(0);

    cur = cur + 1 >= 3 ? 0 : cur + 1;
  }

  const int rl = (lane >> 4) * 4;
  #pragma unroll
  for (int mf = 0; mf < 4; mf++) {
    #pragma unroll
    for (int nf = 0; nf < 4; nf++) {
      #pragma unroll
      for (int r = 0; r < 4; r++) {
        int grow = m0 + wm * 64 + mf * 16 + rl + r;
        int gcol = n0 + wn * 64 + nf * 16 + l15;
        float v = acc[mf][nf][r];
        if (MODE == 0) {
          v += tcs[wn * 64 + nf * 16 + l15];
          outb[(size_t)grow * Ntot + gcol] = f2bf(v);
        } else {
          v += bias[gcol];
          outf[(size_t)grow * Ntot + gcol] = v;
        }
      }
    }
  }
}

// ------- fused per-head RMSNorm + axial RoPE (q,k) + V transpose -------
__global__ __launch_bounds__(256)
void k_rrv(const u16* __restrict__ qkv,
           const float* __restrict__ cos_y, const float* __restrict__ sin_y,
           const float* __restrict__ cos_x, const float* __restrict__ sin_x,
           const float* __restrict__ qn_w, const float* __restrict__ kn_w,
           u16* __restrict__ Qo, u16* __restrict__ Ko, u16* __restrict__ VT) {
  __shared__ u16 t[64 * 68];
  const int n0 = blockIdx.x * 64, h = blockIdx.y, b = blockIdx.z;
  const int bh = b * 16 + h;
  const int lane = threadIdx.x & 63, w = threadIdx.x >> 6;
  const int l15 = lane & 15, lg = lane >> 4;
  float4 qw = *(const float4*)(qn_w + l15 * 4);
  float4 kw = *(const float4*)(kn_w + l15 * 4);
  const float sgn = (lane & 4) ? 1.0f : -1.0f;
  const float* ct = (lane & 8) ? cos_x : cos_y;
  const float* st = (lane & 8) ? sin_x : sin_y;
  const float QSCALE = 0.18033688011112042f;     // log2(e)/8

  #pragma unroll
  for (int rr = 0; rr < 4; rr++) {
    int row = n0 + w * 16 + rr * 4 + lg;
    size_t src = (size_t)(b * 1024 + row) * 3072 + h * 64 + l15 * 4;
    uint2 qu = *(const uint2*)(qkv + src);
    uint2 ku = *(const uint2*)(qkv + src + 1024);
    float q[4], k[4];
    q[0] = bf2f((u16)qu.x); q[1] = bf2f((u16)(qu.x >> 16));
    q[2] = bf2f((u16)qu.y); q[3] = bf2f((u16)(qu.y >> 16));
    k[0] = bf2f((u16)ku.x); k[1] = bf2f((u16)(ku.x >> 16));
    k[2] = bf2f((u16)ku.y); k[3] = bf2f((u16)(ku.y >> 16));
    float sq = q[0]*q[0] + q[1]*q[1] + q[2]*q[2] + q[3]*q[3];
    float sk = k[0]*k[0] + k[1]*k[1] + k[2]*k[2] + k[3]*k[3];
    #pragma unroll
    for (int m = 1; m < 16; m <<= 1) {
      sq += __shfl_xor(sq, m);
      sk += __shfl_xor(sk, m);
    }
    float rq = rsqrtf(sq * (1.0f / 64.0f) + 1e-6f);
    float rk = rsqrtf(sk * (1.0f / 64.0f) + 1e-6f);
    float4 cc = *(const float4*)(ct + (size_t)row * 32 + (lane & 7) * 4);
    float4 ss = *(const float4*)(st + (size_t)row * 32 + (lane & 7) * 4);
    float qn[4], kn[4];
    qn[0] = q[0]*rq*qw.x; qn[1] = q[1]*rq*qw.y; qn[2] = q[2]*rq*qw.z; qn[3] = q[3]*rq*qw.w;
    kn[0] = k[0]*rk*kw.x; kn[1] = k[1]*rk*kw.y; kn[2] = k[2]*rk*kw.z; kn[3] = k[3]*rk*kw.w;
    float c[4] = {cc.x, cc.y, cc.z, cc.w};
    float s[4] = {ss.x, ss.y, ss.z, ss.w};
    union { u16 e[4]; uint2 u; } oq, ok;
    #pragma unroll
    for (int j = 0; j < 4; j++) {
      float qp = __shfl_xor(qn[j], 4);
      float kp = __shfl_xor(kn[j], 4);
      oq.e[j] = f2bf((qn[j] * c[j] + sgn * qp * s[j]) * QSCALE);
      ok.e[j] = f2bf(kn[j] * c[j] + sgn * kp * s[j]);
    }
    size_t dst = ((size_t)bh * 1024 + row) * 64 + l15 * 4;
    *(uint2*)(Qo + dst) = oq.u;
    *(uint2*)(Ko + dst) = ok.u;
  }

  // V transpose: qkv v-slice [n][d] -> VT [bh][d][n]
  #pragma unroll
  for (int i = 0; i < 4; i++) {
    int e = i * 256 + threadIdx.x;
    int n = e >> 4, dc = e & 15;
    uint2 v = *(const uint2*)(qkv + (size_t)(b * 1024 + n0 + n) * 3072 + 2048 + h * 64 + dc * 4);
    t[(dc * 4 + 0) * 68 + n] = (u16)v.x;
    t[(dc * 4 + 1) * 68 + n] = (u16)(v.x >> 16);
    t[(dc * 4 + 2) * 68 + n] = (u16)v.y;
    t[(dc * 4 + 3) * 68 + n] = (u16)(v.y >> 16);
  }
  __syncthreads();
  #pragma unroll
  for (int i = 0; i < 4; i++) {
    int e = i * 256 + threadIdx.x;
    int d = e >> 4, nc = e & 15;
    const u16* p = &t[d * 68 + nc * 4];
    uint2 o;
    o.x = (uint32_t)p[0] | ((uint32_t)p[1] << 16);
    o.y = (uint32_t)p[2] | ((uint32_t)p[3] << 16);
    *(uint2*)(VT + ((size_t)bh * 64 + d) * 1024 + n0 + nc * 4) = o;
  }
}

// ---------------- flash attention, 128 q-rows/block, dbuf K/V, 1 barrier/iter ----------------
__global__ __launch_bounds__(256, 2)
void k_attn(const u16* __restrict__ Q, const u16* __restrict__ Kb,
            const u16* __restrict__ VT, u16* __restrict__ Ob) {
  __shared__ u16 Ks[2][4096], VTs[2][4096], Ps[4][2048];
  const int lane = threadIdx.x & 63;
  const int w = threadIdx.x >> 6;
  const int bh = blockIdx.x;
  const int qt = blockIdx.y;
  const int b = bh >> 4, h = bh & 15;
  const size_t base = (size_t)bh * 65536;
  const int q0 = qt * 128;
  const int scol = ((lane & 7) ^ (lane >> 3)) * 8;
  const int lr = lane >> 3;

  bf16x8 aq[2][2];
  #pragma unroll
  for (int i = 0; i < 2; i++)
    #pragma unroll
    for (int s = 0; s < 2; s++)
      aq[i][s] = *(const bf16x8*)(Q + base +
          (size_t)(q0 + w * 32 + i * 16 + (lane & 15)) * 64 + s * 32 + (lane >> 4) * 8);

  f32x4 acc_o[2][4];
  float lpar[2][4];
  #pragma unroll
  for (int i = 0; i < 2; i++)
    #pragma unroll
    for (int r = 0; r < 4; r++) {
      acc_o[i][r] = (f32x4){0.f, 0.f, 0.f, 0.f};
      lpar[i][r] = 0.f;
    }

  #pragma unroll
  for (int tt = 0; tt < 2; tt++) {
    int t = w * 2 + tt;
    gload16(Kb + base + (size_t)(8 * t + lr) * 64 + scol, &Ks[0][t * 512]);
    gload16(VT + base + (size_t)(8 * t + lr) * 1024 + scol, &VTs[0][t * 512]);
  }

  for (int it = 0; it < 16; it++) {
    __syncthreads();
    const int cur = it & 1;
    if (it < 15) {
      const int nxt = cur ^ 1;
      const int j1 = (it + 1) * 64;
      #pragma unroll
      for (int tt = 0; tt < 2; tt++) {
        int t = w * 2 + tt;
        gload16(Kb + base + (size_t)(j1 + 8 * t + lr) * 64 + scol, &Ks[nxt][t * 512]);
        gload16(VT + base + (size_t)(8 * t + lr) * 1024 + j1 + scol, &VTs[nxt][t * 512]);
      }
    }
    const u16* K_ = Ks[cur];
    const u16* V_ = VTs[cur];

    f32x4 accs[2][4];
    #pragma unroll
    for (int i = 0; i < 2; i++)
      #pragma unroll
      for (int nt = 0; nt < 4; nt++) accs[i][nt] = (f32x4){0.f, 0.f, 0.f, 0.f};
    #pragma unroll
    for (int s = 0; s < 2; s++) {
      bf16x8 bk[4];
      #pragma unroll
      for (int nt = 0; nt < 4; nt++)
        bk[nt] = *(const bf16x8*)&K_[swz(nt * 16 + (lane & 15), s * 32 + (lane >> 4) * 8)];
      __builtin_amdgcn_s_setprio(1);
      #pragma unroll
      for (int i = 0; i < 2; i++)
        #pragma unroll
        for (int nt = 0; nt < 4; nt++)
          accs[i][nt] = mfma16(aq[i][s], bk[nt], accs[i][nt]);
      __builtin_amdgcn_s_setprio(0);
    }

    #pragma unroll
    for (int i = 0; i < 2; i++) {
      #pragma unroll
      for (int nt = 0; nt < 4; nt++) {
        #pragma unroll
        for (int r = 0; r < 4; r++) {
          float p = __builtin_amdgcn_exp2f(accs[i][nt][r]);
          lpar[i][r] += p;
          Ps[w][swz(i * 16 + (lane >> 4) * 4 + r, nt * 16 + (lane & 15))] = f2bf(p);
        }
      }
    }
    asm volatile("s_waitcnt lgkmcnt(0)" ::: "memory");

    #pragma unroll
    for (int s = 0; s < 2; s++) {
      bf16x8 bv[4];
      #pragma unroll
      for (int dt = 0; dt < 4; dt++)
        bv[dt] = *(const bf16x8*)&V_[swz(dt * 16 + (lane & 15), s * 32 + (lane >> 4) * 8)];
      bf16x8 ap0 = *(const bf16x8*)&Ps[w][swz(0 * 16 + (lane & 15), s * 32 + (lane >> 4) * 8)];
      bf16x8 ap1 = *(const bf16x8*)&Ps[w][swz(1 * 16 + (lane & 15), s * 32 + (lane >> 4) * 8)];
      __builtin_amdgcn_s_setprio(1);
      #pragma unroll
      for (int dt = 0; dt < 4; dt++) {
        acc_o[0][dt] = mfma16(ap0, bv[dt], acc_o[0][dt]);
        acc_o[1][dt] = mfma16(ap1, bv[dt], acc_o[1][dt]);
      }
      __builtin_amdgcn_s_setprio(0);
    }
  }

  #pragma unroll
  for (int i = 0; i < 2; i++) {
    float inv[4];
    #pragma unroll
    for (int r = 0; r < 4; r++) {
      float l = lpar[i][r];
      #pragma unroll
      for (int m = 1; m < 16; m <<= 1) l += __shfl_xor(l, m);
      inv[r] = 1.0f / l;
    }
    #pragma unroll
    for (int dt = 0; dt < 4; dt++)
      #pragma unroll
      for (int r = 0; r < 4; r++) {
        int row = q0 + w * 32 + i * 16 + (lane >> 4) * 4 + r;
        int col = h * 64 + dt * 16 + (lane & 15);
        Ob[((size_t)b * 1024 + row) * 1024 + col] = f2bf(acc_o[i][dt][r] * inv[r]);
      }
  }
}

// ---------------- launch ----------------
extern "C" void kernel_launch(void* const* d_in, const int* in_sizes, int n_in,
                              void* d_out, int out_size, void* d_ws, size_t ws_size,
                              hipStream_t stream) {
  const float* x     = (const float*)d_in[0];
  const float* temb  = (const float*)d_in[1];
  const float* cos_y = (const float*)d_in[2];
  const float* sin_y = (const float*)d_in[3];
  const float* cos_x = (const float*)d_in[4];
  const float* sin_x = (const float*)d_in[5];
  const float* Wqkv  = (const float*)d_in[6];
  const float* bqkv  = (const float*)d_in[7];
  const float* Wt    = (const float*)d_in[8];
  const float* bt    = (const float*)d_in[9];
  const float* Wp    = (const float*)d_in[10];
  const float* bp    = (const float*)d_in[11];
  const float* qn_w  = (const float*)d_in[12];
  const float* kn_w  = (const float*)d_in[13];
  float* out = (float*)d_out;

  char* ws = (char*)d_ws;
  u16*   x_bf  = (u16*)(ws);                  // 16 MB; reused as att after QKV GEMM
  u16*   WqkvT = (u16*)(ws + 16777216);       // 6 MB
  u16*   WpT   = (u16*)(ws + 23068672);       // 2 MB
  u16*   qkv   = (u16*)(ws + 25264128);       // 48 MB
  u16*   Qb    = (u16*)(ws + 75595776);       // 16 MB
  u16*   Kb    = (u16*)(ws + 92372992);       // 16 MB
  u16*   VTb   = (u16*)(ws + 109150208);      // 16 MB
  float* tpart = (float*)(ws + 125927424);    // 3 MB
  u16*   att   = x_bf;

  k_prep<<<9600, 256, 0, stream>>>(x, x_bf, Wqkv, WqkvT, Wp, WpT, temb, Wt, tpart);
  k_gemm<0><<<dim3(768), 512, 0, stream>>>(x_bf, WqkvT, qkv, nullptr, nullptr,
                                           bt, bqkv, tpart, 1024, 3072);
  k_rrv<<<dim3(16, 16, 8), 256, 0, stream>>>(qkv, cos_y, sin_y, cos_x, sin_x,
                                             qn_w, kn_w, Qb, Kb, VTb);
  k_attn<<<dim3(128, 8), 256, 0, stream>>>(Qb, Kb, VTb, att);
  k_gemm<1><<<dim3(256), 512, 0, stream>>>(att, WpT, nullptr, out, bp,
                                           nullptr, nullptr, nullptr, 1024, 1024);
}